// Round 7
// baseline (409.056 us; speedup 1.0000x reference)
//
#include <hip/hip_runtime.h>

typedef __attribute__((ext_vector_type(8))) short short8;
typedef __attribute__((ext_vector_type(4))) float f32x4;

constexpr int Bb = 256, Ss = 512, Kk = 32, Ff = 64, H1 = 512, H2 = 256;
constexpr int Mtot = Bb * Ss;   // 131072
constexpr int Mh = Mtot / 2;    // 65536 rows per half
constexpr int KD1 = Kk * Ff;    // 2048

#define DEVI static __device__ __forceinline__
#define BARRIER asm volatile("s_barrier" ::: "memory")
#define VMCNT(N) asm volatile("s_waitcnt vmcnt(" #N ")" ::: "memory")

DEVI unsigned short f2b(float f) {
  unsigned u = __float_as_uint(f);
  return (unsigned short)((u + 0x7FFFu + ((u >> 16) & 1u)) >> 16);
}

DEVI void stage16(const void* g, void* l) {
  __builtin_amdgcn_global_load_lds((const __attribute__((address_space(1))) void*)g,
                                   (__attribute__((address_space(3))) void*)l, 16, 0, 0);
}

// ---------- precompute kernels ----------
__global__ void k_cvt_x(const float* __restrict__ x, unsigned short* __restrict__ xbf) {
  int i = blockIdx.x * 256 + threadIdx.x;
  float4 v = ((const float4*)x)[i];
  ushort4 o;
  o.x = f2b(v.x); o.y = f2b(v.y); o.z = f2b(v.z); o.w = f2b(v.w);
  ((ushort4*)xbf)[i] = o;
}

__global__ void k_w1t(const float* __restrict__ W1, unsigned short* __restrict__ w1t) {
  int idx = blockIdx.x * 256 + threadIdx.x;  // 512*2048
  int h = idx >> 11, i = idx & 2047;
  int k = i >> 6, f = i & 63;
  w1t[idx] = f2b(W1[(k * 65 + f) * 512 + h]);
}

__global__ void k_w2t(const float* __restrict__ W2, unsigned short* __restrict__ w2t) {
  int idx = blockIdx.x * 256 + threadIdx.x;  // 256*512
  int n = idx >> 9, k = idx & 511;
  w2t[idx] = f2b(W2[k * 256 + n]);
}

__global__ void k_dbias(const float* __restrict__ W1, const float* __restrict__ b1,
                        const float* __restrict__ dist, float* __restrict__ dbias) {
  int idx = blockIdx.x * 256 + threadIdx.x;  // 512*512
  int s = idx >> 9, h = idx & 511;
  float a = b1[h];
  #pragma unroll
  for (int k = 0; k < 32; ++k)
    a += dist[s * 32 + k] * W1[(k * 65 + 64) * 512 + h];
  dbias[idx] = a;
}

// ---------- GEMM1 (batch-major, 4-slot halfK rotation, 1 barrier/window) ----------
// Tile: 256 batches x 256 cols at ONE s. K = 2048 = 64 halfK windows of 32.
// sigma-layout of a 16-KB halfK region (256 rows x 32 cols bf16, rows=64B):
//   chunk sigma(r,c) = (r>>1)*8 + ((c + 4*(r&1)) ^ ((r>>1)&7))
// Staged linearly (unit U: sigma = U*512 + w*64 + lane), read with same formula.
// Pipeline: window W stages W+3 (4 loads/thread), VMCNT(8) => W+1 complete
// before next barrier; ONE s_barrier per window (buffer rotation WAR fence).
__global__ __launch_bounds__(512, 2) void k_gemm1(
    const unsigned short* __restrict__ xbf, const unsigned short* __restrict__ w1t,
    const int* __restrict__ nb, const float* __restrict__ dbias,
    unsigned short* __restrict__ h1, int sbase) {
  __shared__ __align__(16) unsigned short lds[4][2][8192];  // [slot][A,B][16KB]
  __shared__ int jlds[32];
  const int tid = threadIdx.x;
  const int lane = tid & 63;
  const int w = tid >> 6;            // 0..7
  const int wm = w >> 2, wn = w & 3;
  const int sblk = blockIdx.x >> 1;  // 0..255
  const int s = sbase + sblk;
  const int nblk = blockIdx.x & 1;
  const int ncol0 = nblk << 8;
  const int ds = sblk;               // local s within half

  if (tid < 32) jlds[tid] = nb[(s << 5) + tid];

  // staging geometry (per-lane constants)
  const int slotb = (lane & 7) ^ (lane >> 3);
  const int rSt = (w << 4) + ((lane >> 3) << 1) + (slotb >> 2);  // + U*128
  const int cSt8 = (slotb & 3) << 3;                             // element offset
  const size_t aBase0 = ((size_t)rSt << 15);
  const size_t aBase1 = ((size_t)(rSt + 128) << 15);
  const size_t bBase0 = ((size_t)(ncol0 + rSt) << 11);
  const size_t bBase1 = ((size_t)(ncol0 + rSt + 128) << 11);
  const int dstL = (w << 9) + (lane << 3);                       // elems within unit row

  // frag-read geometry
  const int r0 = lane & 15, cF = lane >> 4;
  const int q0 = r0 >> 1;
  const int sl0 = cF + ((r0 & 1) << 2);
  const int sig0e = (((q0 << 3) + (sl0 ^ q0)) << 3);             // elems
  const int sA0 = (wm << 12) + sig0e;
  const int sB0 = (wn << 11) + sig0e;

  f32x4 acc[8][4];
  #pragma unroll
  for (int m = 0; m < 8; ++m)
    #pragma unroll
    for (int n = 0; n < 4; ++n) acc[m][n] = (f32x4){0.f, 0.f, 0.f, 0.f};

  __syncthreads();   // jlds visible

#define STAGE_WIN(WIN)                                                          \
  {                                                                             \
    const int HS = ((WIN) < 63) ? (WIN) : 63;                                   \
    const int tS = HS >> 1, hS = HS & 1;                                        \
    const int slS = (WIN) & 3;                                                  \
    const int jS = jlds[tS];                                                    \
    const size_t ko = ((size_t)hS << 5) + cSt8;                                 \
    const size_t ja = ((size_t)jS << 6);                                        \
    stage16(xbf + aBase0 + ja + ko, &lds[slS][0][dstL]);                        \
    stage16(xbf + aBase1 + ja + ko, &lds[slS][0][4096 + dstL]);                 \
    stage16(w1t + bBase0 + ((size_t)HS << 5) + cSt8, &lds[slS][1][dstL]);       \
    stage16(w1t + bBase1 + ((size_t)HS << 5) + cSt8, &lds[slS][1][4096 + dstL]); \
  }

  // prologue: stage windows 0,1,2
  STAGE_WIN(0);
  STAGE_WIN(1);
  STAGE_WIN(2);
  VMCNT(8);          // window 0 landed

  #pragma unroll 4
  for (int W = 0; W < 64; ++W) {
    BARRIER;         // publishes window W data (all waves vmcnt'd it last iter)
    const int sl4 = W & 3;
    const unsigned short* Ar = &lds[sl4][0][0];
    const unsigned short* Br = &lds[sl4][1][0];
    short8 a0[4], a1[4], bF[4];
    #pragma unroll
    for (int i = 0; i < 4; ++i) a0[i] = *(const short8*)(Ar + sA0 + (i << 9));
    #pragma unroll
    for (int n = 0; n < 4; ++n) bF[n] = *(const short8*)(Br + sB0 + (n << 9));
    #pragma unroll
    for (int i = 0; i < 4; ++i) a1[i] = *(const short8*)(Ar + sA0 + 2048 + (i << 9));

    STAGE_WIN(W + 3);   // into slot (W+3)&3 == (W-1)&3 (dead after last barrier)
    VMCNT(8);           // window W+1 fully landed before next barrier

    __builtin_amdgcn_s_setprio(1);
    #pragma unroll
    for (int i = 0; i < 4; ++i)
      #pragma unroll
      for (int n = 0; n < 4; ++n)
        acc[i][n] = __builtin_amdgcn_mfma_f32_16x16x32_bf16(a0[i], bF[n], acc[i][n], 0, 0, 0);
    #pragma unroll
    for (int i = 0; i < 4; ++i)
      #pragma unroll
      for (int n = 0; n < 4; ++n)
        acc[4 + i][n] = __builtin_amdgcn_mfma_f32_16x16x32_bf16(a1[i], bF[n], acc[4 + i][n], 0, 0, 0);
    __builtin_amdgcn_s_setprio(0);
  }
#undef STAGE_WIN

  // epilogue: relu(acc + dbias[s][col]) -> h1[(batch*256 + ds)*512 + col]
  #pragma unroll
  for (int n = 0; n < 4; ++n) {
    const int col = ncol0 + (wn << 6) + (n << 4) + (lane & 15);
    const float dv = dbias[(s << 9) + col];
    #pragma unroll
    for (int fm = 0; fm < 8; ++fm) {
      const int rbase = (wm << 7) + ((fm >> 2) << 6) + ((fm & 3) << 4) + ((lane >> 4) << 2);
      #pragma unroll
      for (int r = 0; r < 4; ++r) {
        const int batch = rbase + r;
        float v = acc[fm][n][r] + dv;
        v = v > 0.f ? v : 0.f;
        h1[(((size_t)((batch << 8) + ds)) << 9) + col] = f2b(v);
      }
    }
  }
}

// ---------- GEMM2 (BN=256 single-pass) + fused max-over-S ----------
// h1 local layout: [batch][ds=256][512]; tile = 128 consecutive rows = one batch.
__global__ __launch_bounds__(256, 2) void k_gemm2(
    const unsigned short* __restrict__ h1, const unsigned short* __restrict__ w2t,
    const float* __restrict__ b2, unsigned* __restrict__ mrelu) {
  __shared__ __align__(16) unsigned short As[128 * 64];   // 16 KB
  __shared__ __align__(16) unsigned short Bs[256 * 64];   // 32 KB
  const int tid = threadIdx.x;
  const int lane = tid & 63;
  const int w = tid >> 6;            // 0..3, wave covers cols w*64..+63
  const int r0l = blockIdx.x << 7;
  const int b = r0l >> 8;            // batch of this tile
  const int scol8 = (((lane & 7) ^ ((lane >> 3) & 7)) << 3);

  f32x4 acc[8][4];
  #pragma unroll
  for (int m = 0; m < 8; ++m)
    #pragma unroll
    for (int n = 0; n < 4; ++n) acc[m][n] = (f32x4){0.f, 0.f, 0.f, 0.f};

  for (int t = 0; t < 8; ++t) {
    #pragma unroll
    for (int a2 = 0; a2 < 4; ++a2)
      stage16(h1 + (((size_t)(r0l + (w << 5) + (a2 << 3) + (lane >> 3))) << 9) +
                  (t << 6) + scol8,
              As + (w << 11) + (a2 << 9));
    #pragma unroll
    for (int b2i = 0; b2i < 8; ++b2i)
      stage16(w2t + (((size_t)((w << 6) + (b2i << 3) + (lane >> 3))) << 9) +
                  (t << 6) + scol8,
              Bs + (w << 12) + (b2i << 9));
    VMCNT(0);
    __syncthreads();
    #pragma unroll
    for (int ks = 0; ks < 2; ++ks) {
      const int rdoff = ((((ks << 2) + (lane >> 4)) ^ (lane & 7)) << 3);
      short8 af[8], bf[4];
      #pragma unroll
      for (int fm = 0; fm < 8; ++fm)
        af[fm] = *(const short8*)(As + ((fm << 4) + (lane & 15)) * 64 + rdoff);
      #pragma unroll
      for (int n = 0; n < 4; ++n)
        bf[n] = *(const short8*)(Bs + ((w << 6) + (n << 4) + (lane & 15)) * 64 + rdoff);
      #pragma unroll
      for (int fm = 0; fm < 8; ++fm)
        #pragma unroll
        for (int n = 0; n < 4; ++n)
          acc[fm][n] = __builtin_amdgcn_mfma_f32_16x16x32_bf16(af[fm], bf[n], acc[fm][n], 0, 0, 0);
    }
    __syncthreads();
  }

  #pragma unroll
  for (int n = 0; n < 4; ++n) {
    int col = (w << 6) + (n << 4) + (lane & 15);
    float cm = -1e30f;
    #pragma unroll
    for (int fm = 0; fm < 8; ++fm)
      #pragma unroll
      for (int r = 0; r < 4; ++r) cm = fmaxf(cm, acc[fm][n][r]);
    cm = fmaxf(cm, __shfl_xor(cm, 16));
    cm = fmaxf(cm, __shfl_xor(cm, 32));
    if ((lane >> 4) == 0) {
      float v = fmaxf(cm + b2[col], 0.f);
      atomicMax(mrelu + ((b << 8) + col), __float_as_uint(v));
    }
  }
}

// ---------- final: out[b] = relu(m[b,:]) . Wd + bd ----------
__global__ void k_final(const unsigned* __restrict__ mrelu, const float* __restrict__ wd,
                        const float* __restrict__ bd, float* __restrict__ out) {
  int b = blockIdx.x, t = threadIdx.x;
  float v = __uint_as_float(mrelu[(b << 8) + t]) * wd[t];
  #pragma unroll
  for (int o = 32; o > 0; o >>= 1) v += __shfl_down(v, o);
  __shared__ float p[4];
  if ((t & 63) == 0) p[t >> 6] = v;
  __syncthreads();
  if (t == 0) out[b] = p[0] + p[1] + p[2] + p[3] + bd[0];
}

extern "C" void kernel_launch(void* const* d_in, const int* in_sizes, int n_in,
                              void* d_out, int out_size, void* d_ws, size_t ws_size,
                              hipStream_t stream) {
  (void)in_sizes; (void)n_in; (void)out_size; (void)ws_size;
  const float* x    = (const float*)d_in[0];
  const int*   nb   = (const int*)d_in[1];
  const float* dist = (const float*)d_in[2];
  const float* W1   = (const float*)d_in[3];
  const float* b1   = (const float*)d_in[4];
  const float* W2   = (const float*)d_in[5];
  const float* b2   = (const float*)d_in[6];
  const float* Wd   = (const float*)d_in[7];
  const float* bd   = (const float*)d_in[8];
  float* out = (float*)d_out;

  // ws usage: 16 + 2 + 0.25 + 1 + 0.25 + 64 = ~83.6 MB
  char* p = (char*)d_ws;
  unsigned short* xbf   = (unsigned short*)p; p += (size_t)Bb * Ss * Ff * 2;
  unsigned short* w1t   = (unsigned short*)p; p += (size_t)H1 * KD1 * 2;
  unsigned short* w2t   = (unsigned short*)p; p += (size_t)H2 * H1 * 2;
  float*          dbias = (float*)p;          p += (size_t)Ss * H1 * 4;
  unsigned*       mrelu = (unsigned*)p;       p += (size_t)Bb * H2 * 4;
  unsigned short* h1    = (unsigned short*)p; p += (size_t)Mh * H1 * 2;

  hipMemsetAsync(mrelu, 0, (size_t)Bb * H2 * 4, stream);
  k_cvt_x<<<(Bb * Ss * Ff / 4) / 256, 256, 0, stream>>>(x, xbf);
  k_w1t<<<(H1 * KD1) / 256, 256, 0, stream>>>(W1, w1t);
  k_w2t<<<(H2 * H1) / 256, 256, 0, stream>>>(W2, w2t);
  k_dbias<<<(Ss * H1) / 256, 256, 0, stream>>>(W1, b1, dist, dbias);
  for (int hh = 0; hh < 2; ++hh) {
    k_gemm1<<<512, 512, 0, stream>>>(xbf, w1t, nb, dbias, h1, hh * 256);
    k_gemm2<<<Mh / 128, 256, 0, stream>>>(h1, w2t, b2, mrelu);
  }
  k_final<<<Bb, 256, 0, stream>>>(mrelu, Wd, bd, out);
}